// Round 8
// baseline (1383.162 us; speedup 1.0000x reference)
//
#include <hip/hip_runtime.h>
#include <stdint.h>

// ---------- types ----------
typedef __attribute__((ext_vector_type(8)))  __bf16 bf16x8;   // MFMA A/B frag (4 VGPRs)
typedef __attribute__((ext_vector_type(4)))  float  f32x4;    // 16x16 MFMA C/D frag
typedef __attribute__((ext_vector_type(16))) float  f32x16;   // 32x32 MFMA C/D frag
typedef unsigned short u16;
typedef __attribute__((ext_vector_type(8))) unsigned short u16x8;

#define GLOBAL_AS __attribute__((address_space(1)))
#define LDS_AS    __attribute__((address_space(3)))

__device__ __forceinline__ void load_lds16(const void* g, void* l) {
    __builtin_amdgcn_global_load_lds((const GLOBAL_AS void*)g, (LDS_AS void*)l, 16, 0, 0);
}

__device__ __forceinline__ u16 f2bf(float f) {
    union { float f; uint32_t u; } v; v.f = f;
    uint32_t r = v.u + 0x7FFFu + ((v.u >> 16) & 1u);   // RNE
    return (u16)(r >> 16);
}
__device__ __forceinline__ float b2f(u16 b) {
    union { uint32_t u; float f; } v; v.u = ((uint32_t)b) << 16;
    return v.f;
}

// ---------- aux: fp32 -> bf16 convert with zero-padding ----------
__global__ void k_conv_pad(const float* __restrict__ in, u16* __restrict__ out,
                           int rIn, int cIn, int cOut, int total8) {
    int idx = blockIdx.x * blockDim.x + threadIdx.x;
    if (idx >= total8) return;
    int c8n = cOut >> 3;
    int r  = idx / c8n;
    int c0 = (idx - r * c8n) << 3;
    u16x8 o;
#pragma unroll
    for (int j = 0; j < 8; ++j) {
        int c = c0 + j;
        o[j] = (r < rIn && c < cIn) ? f2bf(in[(size_t)r * cIn + c]) : (u16)0;
    }
    *(u16x8*)(out + (size_t)r * cOut + c0) = o;
}

// ---------- aux: fp32 [kIn x nIn] -> bf16 transposed [nOut x kOut], zero-padded ----------
__global__ void k_transpose_conv(const float* __restrict__ in, u16* __restrict__ out,
                                 int kIn, int nIn, int kOut) {
    __shared__ float tile[32][33];
    int k0 = blockIdx.x * 32, n0 = blockIdx.y * 32;
    int tx = threadIdx.x, ty = threadIdx.y;   // block (32,8)
#pragma unroll
    for (int i = 0; i < 4; ++i) {
        int k = k0 + ty + i * 8, n = n0 + tx;
        tile[ty + i * 8][tx] = (k < kIn && n < nIn) ? in[(size_t)k * nIn + n] : 0.f;
    }
    __syncthreads();
#pragma unroll
    for (int i = 0; i < 4; ++i) {
        int n = n0 + ty + i * 8, k = k0 + tx;
        out[(size_t)n * kOut + k] = f2bf(tile[tx][ty + i * 8]);
    }
}

// ---------- old 128x128 kernel (kept for G3: proven ~97us at 4 blocks/CU) ----------
template <int MODE>
__global__ __launch_bounds__(256, 4) void k_gemm_bt(
    const u16* __restrict__ A, const u16* __restrict__ B,
    const u16* __restrict__ bias, void* __restrict__ Cv,
    int K, int ldc, int mReal, int nReal) {
    (void)bias;
    __shared__ __align__(16) char lds[32768];
    char* As = lds;
    char* Bs = lds + 16384;

    const int tid  = threadIdx.x;
    const int w    = tid >> 6, lane = tid & 63;
    const int l31  = lane & 31, hi = lane >> 5;
    const int wm   = (w & 1) * 64, wn = (w >> 1) * 64;
    const int bm   = blockIdx.y * 128, bn = blockIdx.x * 128;

    const int srcRow = tid >> 3;
    const int srcCol = (tid & 7) ^ (srcRow & 7);
    const u16* aSrc = A + (size_t)(bm + srcRow) * K + (srcCol << 3);
    const u16* bSrc = B + (size_t)(bn + srcRow) * K + (srcCol << 3);
    char* aDst = As + ((tid & ~63) << 4);
    char* bDst = Bs + ((tid & ~63) << 4);

    const int aRow0 = (wm + l31) * 128;
    const int aRow1 = (wm + 32 + l31) * 128;
    const int bRow0 = (wn + l31) * 128;
    const int bRow1 = (wn + 32 + l31) * 128;

    f32x16 acc[2][2];
#pragma unroll
    for (int i = 0; i < 2; ++i)
#pragma unroll
        for (int j = 0; j < 2; ++j) acc[i][j] = (f32x16)(0.f);

    for (int k0 = 0; k0 < K; k0 += 64) {
#pragma unroll
        for (int t = 0; t < 4; ++t) {
            load_lds16(aSrc + (size_t)(t * 32) * K, aDst + t * 4096);
            load_lds16(bSrc + (size_t)(t * 32) * K, bDst + t * 4096);
        }
        aSrc += 64; bSrc += 64;
        __syncthreads();
#pragma unroll
        for (int ks = 0; ks < 4; ++ks) {
            const int swz = (((ks * 2 + hi) ^ (l31 & 7)) << 4);
            bf16x8 af[2], bfr[2];
            af[0]  = *(const bf16x8*)(As + aRow0 + swz);
            af[1]  = *(const bf16x8*)(As + aRow1 + swz);
            bfr[0] = *(const bf16x8*)(Bs + bRow0 + swz);
            bfr[1] = *(const bf16x8*)(Bs + bRow1 + swz);
#pragma unroll
            for (int mi = 0; mi < 2; ++mi)
#pragma unroll
                for (int ni = 0; ni < 2; ++ni)
                    acc[mi][ni] = __builtin_amdgcn_mfma_f32_32x32x16_bf16(
                        af[mi], bfr[ni], acc[mi][ni], 0, 0, 0);
        }
        __syncthreads();
    }

    float bv[2];
    if (MODE >= 1) {
#pragma unroll
        for (int ni = 0; ni < 2; ++ni) bv[ni] = b2f(bias[bn + wn + ni * 32 + l31]);
    }
#pragma unroll
    for (int mi = 0; mi < 2; ++mi) {
#pragma unroll
        for (int reg = 0; reg < 16; ++reg) {
            int row = bm + wm + mi * 32 + (reg & 3) + 8 * (reg >> 2) + 4 * hi;
#pragma unroll
            for (int ni = 0; ni < 2; ++ni) {
                int col = bn + wn + ni * 32 + l31;
                float v = acc[mi][ni][reg];
                if (MODE == 0) {
                    if (row < mReal && col < nReal)
                        ((u16*)Cv)[(size_t)row * ldc + col] = f2bf(v);
                } else if (MODE == 1) {
                    v += bv[ni];
                    v = v > 0.f ? v : 0.f;
                    ((u16*)Cv)[(size_t)row * ldc + col] = f2bf(v);
                } else {
                    ((float*)Cv)[(size_t)row * ldc + col] = v + bv[ni];
                }
            }
        }
    }
}

// ---------- 256x256 8-phase GEMM, R8: one-phase-ahead reads + counted lgkm ----------
// R7 post-mortem: conflicts = 0 but per-block MfmaUtil ~50% — the per-phase
// {reads; bar; lgkm0; MFMA} structure SERIALIZES LDS service (~4600 cyc/iter at
// 85 B/cyc) with MFMA (~4970 cyc/iter). Fix: issue phase p's reads during p-1,
// wait with lgkmcnt(|reads just issued|) so the LDS pipe services next-phase
// reads DURING MFMA. Quadrant order per tile: Q00->Q10->Q11->Q01 (min liveness;
// per-acc accumulation order unchanged -> numerics identical to R7).
// Register sets (alternate per half-iter): aP: a0(even)/a1'(odd); aQ: a1(even)/
// a0'(odd); bP: b0/b0'; bQ: b1/b1'. Peak live frags 24 (96 VGPR) + acc 128.
// Read-issue schedule (issue(p) consumed by MFMA(p+1)); lgkm count = |issue(p)|:
//   pre: a0,b0[12] | ph1: a1[8] | ph2: b1[4] | ph3: -[0] | ph4: a0',b0'[12]
//   ph5: a1'[8] | ph6: b1'[4] | ph7: -[0] | ph8: a0n,b0n[12]
// Drain points (all-waves at that phase's trailing barrier):
//   buf0.A: ph2 | buf0.B: ph3 | buf1.A: ph6 | buf1.B: ph7
// Stage slots (earliest legal; iter J holds tiles 2J,2J+1):
//   ph1: buf1.B1<-2J+1 | ph3: buf0.A0<-2J+2 | ph4: buf0.A1+buf0.B0 | ph5: buf0.B1
//   ph7: buf1.A0<-2J+3 | ph8: buf1.A1+buf1.B0   (buf1.B1 closes at next ph1)
// VMCNT checkpoints (before reads of a freshly staged buffer, + barrier):
//   ph3: VMCNT(2) keeps own stage, drains prev7/prev8/ph1 = buf1 -> ph4 reads ok
//   ph7: VMCNT(2) keeps own stage, drains ph3/ph4/ph5 = buf0 -> ph8 reads ok
//   last iter: ph3 VMCNT(0) (no own stage); ph7/ph8 no stages, lgkm0 at ph8.
// Prologue: tile0 full + tile1 {A0,A1,B0} = 14 loads; VMCNT(6) drains tile0;
// barrier; issue a0,b0. One barrier per phase (8/iter, was 16).

#define BARRIER() do { asm volatile("" ::: "memory"); \
                       __builtin_amdgcn_s_barrier(); \
                       asm volatile("" ::: "memory"); } while (0)
#define LGKM0()   do { asm volatile("s_waitcnt lgkmcnt(0)" ::: "memory"); \
                       __builtin_amdgcn_sched_barrier(0); } while (0)
#define LGKM4()   do { asm volatile("s_waitcnt lgkmcnt(4)" ::: "memory"); \
                       __builtin_amdgcn_sched_barrier(0); } while (0)
#define LGKM8()   do { asm volatile("s_waitcnt lgkmcnt(8)" ::: "memory"); \
                       __builtin_amdgcn_sched_barrier(0); } while (0)
#define LGKM12()  do { asm volatile("s_waitcnt lgkmcnt(12)" ::: "memory"); \
                       __builtin_amdgcn_sched_barrier(0); } while (0)
#define VMCNT(n)  do { asm volatile("s_waitcnt vmcnt(" #n ")" ::: "memory"); \
                       __builtin_amdgcn_sched_barrier(0); } while (0)

// stage one A-half / B-half (2 x global_load_lds, sweeps of 64 rows each)
#define STG_A(BUFB, H, KT) do { \
    load_lds16(aStage + (size_t)((H) * 128)      * K + (KT), lds + (BUFB) * 65536 + (H) * 16384 +        ldsW); \
    load_lds16(aStage + (size_t)((H) * 128 + 64) * K + (KT), lds + (BUFB) * 65536 + (H) * 16384 + 8192 + ldsW); \
} while (0)
#define STG_B(BUFB, H, KT) do { \
    load_lds16(bStage + (size_t)((H) * 128)      * K + (KT), lds + (BUFB) * 65536 + 32768 + (H) * 16384 +        ldsW); \
    load_lds16(bStage + (size_t)((H) * 128 + 64) * K + (KT), lds + (BUFB) * 65536 + 32768 + (H) * 16384 + 8192 + ldsW); \
} while (0)

// frag reads into named dst: A quadrant MH (8 reads), B quadrant NH (4 reads)
#define RDA(BUFB, MH, DST) do { \
    _Pragma("unroll") for (int m2 = 0; m2 < 4; ++m2) { \
        DST[m2][0] = *(const bf16x8*)(lds + (BUFB) * 65536 + aWave + (MH) * 8192 + m2 * 2048 + laneF); \
        DST[m2][1] = *(const bf16x8*)(lds + (BUFB) * 65536 + aWave + (MH) * 8192 + m2 * 2048 + (laneF ^ 64)); \
    } } while (0)
#define RDB(BUFB, NH, DST) do { \
    _Pragma("unroll") for (int n2 = 0; n2 < 2; ++n2) { \
        DST[n2][0] = *(const bf16x8*)(lds + (BUFB) * 65536 + bWave + (NH) * 4096 + n2 * 2048 + laneF); \
        DST[n2][1] = *(const bf16x8*)(lds + (BUFB) * 65536 + bWave + (NH) * 4096 + n2 * 2048 + (laneF ^ 64)); \
    } } while (0)

// one C-quadrant x K=64: 16 MFMA (8 indep chains per kstep)
#define MM16(AA, BB, MH, NH) do { \
    __builtin_amdgcn_s_setprio(1); \
    _Pragma("unroll") for (int ks = 0; ks < 2; ++ks) \
    _Pragma("unroll") for (int n2 = 0; n2 < 2; ++n2) \
    _Pragma("unroll") for (int m2 = 0; m2 < 4; ++m2) \
        acc[(MH) * 4 + m2][(NH) * 2 + n2] = __builtin_amdgcn_mfma_f32_16x16x32_bf16( \
            AA[m2][ks], BB[n2][ks], acc[(MH) * 4 + m2][(NH) * 2 + n2], 0, 0, 0); \
    __builtin_amdgcn_s_setprio(0); \
} while (0)

template <int MODE>
__global__ __launch_bounds__(512, 2) void k_gemm8p(
    const u16* __restrict__ A, const u16* __restrict__ B,
    const u16* __restrict__ bias, void* __restrict__ Cv,
    int K, int ldc, int mReal, int nReal, int gx, int nTiles) {
    __shared__ __align__(16) char lds[131072];

    const int tid  = threadIdx.x;
    const int w    = tid >> 6, lane = tid & 63;
    const int wc   = w & 3, wr = w >> 2;            // 2M x 4N waves, per-wave 128x64
    const int l15  = lane & 15, lg4 = lane >> 4;

    // bijective XCD-chunked swizzle (m204 form)
    const int nwg = (int)gridDim.x;
    const int q   = nwg >> 3, r = nwg & 7;
    const int xcd = (int)blockIdx.x & 7, lid = (int)blockIdx.x >> 3;
    const int wg0 = (xcd < r ? xcd * (q + 1) : r * (q + 1) + (xcd - r) * q) + lid;

    // frag-read lane offset: row = l&15, chunk slot = ((l>>4) ^ (l&7)); ^64 => kstep1
    const int laneF = l15 * 128 + (((lane >> 4) ^ (lane & 7)) << 4);
    const int aWave = wr * 16384;                                   // A-half = wr
    const int bWave = 32768 + (wc >> 1) * 16384 + (wc & 1) * 8192;  // B-half = wc>>1

    // staging geometry: lane covers (row = w*8 + lane>>3 [+64/sweep], chunk cOrig)
    const int cOrig = (lane & 7) ^ ((lane >> 3) & 7);
    const int sRow  = w * 8 + (lane >> 3);
    const int ldsW  = w * 1024;                      // wave-uniform LDS slot

    const int nIt = K >> 7;                          // iterations of 2 K-tiles

    for (int v = wg0; v < nTiles; v += (int)gridDim.x) {
        const int bm = (v / gx) * 256;
        const int bn = (v % gx) * 256;
        const u16* const aStage = A + (size_t)(bm + sRow) * K + cOrig * 8;
        const u16* const bStage = B + (size_t)(bn + sRow) * K + cOrig * 8;

        f32x4 acc[8][4];
#pragma unroll
        for (int i = 0; i < 8; ++i)
#pragma unroll
            for (int j = 0; j < 4; ++j) acc[i][j] = (f32x4)(0.f);

        bf16x8 aP[4][2], aQ[4][2], bP[2][2], bQ[2][2];

        // prologue: tile0 full + tile1 {A0,A1,B0} = 14 loads; VMCNT(6) => tile0 landed
        STG_A(0, 0, 0);  STG_A(0, 1, 0);  STG_B(0, 0, 0);  STG_B(0, 1, 0);
        STG_A(1, 0, 64); STG_A(1, 1, 64); STG_B(1, 0, 64);
        VMCNT(6);
        BARRIER();
        RDA(0, 0, aP); RDB(0, 0, bP);    // reads for ph1 (12 outstanding)

#pragma unroll 1
        for (int it = 0; it < nIt; ++it) {
            const bool ok = (it + 1 < nIt);
            const size_t kT1 = (size_t)(2 * it + 1) * 64;
            const size_t kS  = (size_t)(2 * it + 2) * 64;
            // ph1: MFMA Q00(a0,b0); stage buf1.B1<-2J+1; issue a1
            STG_B(1, 1, kT1);
            RDA(0, 1, aQ);
            LGKM8(); MM16(aP, bP, 0, 0); BARRIER();
            // ph2: Q10(a1,b0); issue b1
            RDB(0, 1, bQ);
            LGKM4(); MM16(aQ, bP, 1, 0); BARRIER();
            // ph3: Q11(a1,b1); stage buf0.A0<-2J+2; CHECKPOINT: drain buf1 stages
            if (ok) { STG_A(0, 0, kS); VMCNT(2); } else { VMCNT(0); }
            LGKM0(); MM16(aQ, bQ, 1, 1); BARRIER();
            // ph4: Q01(a0,b1); stage buf0.A1 + buf0.B0; issue a0',b0' (buf1 safe)
            if (ok) { STG_A(0, 1, kS); STG_B(0, 0, kS); }
            RDA(1, 0, aQ); RDB(1, 0, bP);
            LGKM12(); MM16(aP, bQ, 0, 1); BARRIER();
            // ph5: Q00'(a0',b0'); stage buf0.B1; issue a1'
            if (ok) { STG_B(0, 1, kS); }
            RDA(1, 1, aP);
            LGKM8(); MM16(aQ, bP, 0, 0); BARRIER();
            // ph6: Q10'(a1',b0'); issue b1'
            RDB(1, 1, bQ);
            LGKM4(); MM16(aP, bP, 1, 0); BARRIER();
            // ph7: Q11'(a1',b1'); stage buf1.A0<-2J+3; CHECKPOINT: drain buf0 stages
            if (ok) { STG_A(1, 0, kS + 64); VMCNT(2); }
            LGKM0(); MM16(aP, bQ, 1, 1); BARRIER();
            // ph8: Q01'(a0',b1'); stage buf1.A1 + buf1.B0; issue a0n,b0n (buf0 safe)
            if (ok) {
                STG_A(1, 1, kS + 64); STG_B(1, 0, kS + 64);
                RDA(0, 0, aP); RDB(0, 0, bP);
                LGKM12();
            } else {
                LGKM0();
            }
            MM16(aQ, bQ, 0, 1); BARRIER();
        }

        // epilogue. 16x16 C/D layout (m89/m91): col = lane&15, row = (lane>>4)*4 + reg
        float bv[4];
        if (MODE >= 1) {
#pragma unroll
            for (int ni = 0; ni < 4; ++ni) bv[ni] = b2f(bias[bn + wc * 64 + ni * 16 + l15]);
        }
#pragma unroll
        for (int mi = 0; mi < 8; ++mi) {
#pragma unroll
            for (int ni = 0; ni < 4; ++ni) {
#pragma unroll
                for (int rg = 0; rg < 4; ++rg) {
                    const int row = bm + wr * 128 + mi * 16 + lg4 * 4 + rg;
                    const int col = bn + wc * 64 + ni * 16 + l15;
                    float vv = acc[mi][ni][rg];
                    if (MODE == 0) {
                        if (row < mReal && col < nReal)
                            ((u16*)Cv)[(size_t)row * ldc + col] = f2bf(vv);
                    } else if (MODE == 1) {
                        vv += bv[ni];
                        vv = vv > 0.f ? vv : 0.f;
                        ((u16*)Cv)[(size_t)row * ldc + col] = f2bf(vv);
                    } else {
                        ((float*)Cv)[(size_t)row * ldc + col] = vv + bv[ni];
                    }
                }
            }
        }
    }
}

// ---------- launch ----------
// Sizes: D_IN=2048, D_H=4096, D_OUT=2048, B=4096; SIZE_N=5794, SIZE_M=2897
// Padded GEMM0 dims: M=N=5888 (23*256), K=2944 (23*128)
// Vf flat unpack offsets (elems):
//   W1 @ 0, b1 @ 8388608, W2 @ 8392704, b2 @ 25169920, W3 @ 25174016, b3 @ 33562624
extern "C" void kernel_launch(void* const* d_in, const int* in_sizes, int n_in,
                              void* d_out, int out_size, void* d_ws, size_t ws_size,
                              hipStream_t stream) {
    (void)in_sizes; (void)n_in; (void)out_size; (void)ws_size;
    const float* x  = (const float*)d_in[0];
    const float* V1 = (const float*)d_in[1];
    const float* V2 = (const float*)d_in[2];

    char* ws = (char*)d_ws;
    u16* Vf   = (u16*)(ws);                            // 5794*5794 bf16 -> 67,140,872 B
    u16* V1b  = (u16*)(ws + 67141120);                 // [5888 x 2944] bf16 = 34,668,544 B
    u16* V2bT = (u16*)(ws + 67141120 + 34668544);      // [5888 x 2944] bf16
    u16* Xb   = (u16*)(ws + 67141120 + 2 * 34668544);  // [4096 x 2048] bf16
    u16* H1   = V1b;   // dead after GEMM0
    u16* H2   = V2bT;

    k_conv_pad<<<8464, 256, 0, stream>>>(V1, V1b, 5794, 2897, 2944, 5888 * 2944 / 8);
    k_transpose_conv<<<dim3(92, 184), dim3(32, 8), 0, stream>>>(V2, V2bT, 2897, 5794, 2944);
    k_conv_pad<<<4096, 256, 0, stream>>>(x, Xb, 4096, 2048, 2048, 4096 * 2048 / 8);

    // G0: Vf = V1 @ V2  (padded 5888x5888x2944; 529 tiles persistent over 512 blocks)
    k_gemm8p<0><<<512, 512, 0, stream>>>(V1b, V2bT, nullptr, Vf,
                                         2944, 5794, 5794, 5794, 23, 529);
    // G1: H1 = relu(Xb @ W1^T + b1)   [4096x4096], K=2048 (16x16 = 256 tiles, 1 round)
    k_gemm8p<1><<<256, 512, 0, stream>>>(Xb, Vf + 0, Vf + 8388608, H1,
                                         2048, 4096, 4096, 4096, 16, 256);
    // G2: H2 = relu(H1 @ W2^T + b2)   [4096x4096], K=4096
    k_gemm8p<1><<<256, 512, 0, stream>>>(H1, Vf + 8392704, Vf + 25169920, H2,
                                         4096, 4096, 4096, 4096, 16, 256);
    // G3: out = H2 @ W3^T + b3        [4096x2048] fp32, K=4096 (old 128^2 kernel)
    k_gemm_bt<2><<<dim3(16, 32), 256, 0, stream>>>(H2, Vf + 25174016, Vf + 33562624, d_out,
                                                   4096, 2048, 4096, 2048);
}

// Round 9
// 728.477 us; speedup vs baseline: 1.8987x; 1.8987x over previous
//
#include <hip/hip_runtime.h>
#include <stdint.h>

// ---------- types ----------
typedef __attribute__((ext_vector_type(8)))  __bf16 bf16x8;   // MFMA A/B frag (4 VGPRs)
typedef __attribute__((ext_vector_type(4)))  float  f32x4;    // 16x16 MFMA C/D frag
typedef __attribute__((ext_vector_type(16))) float  f32x16;   // 32x32 MFMA C/D frag
typedef unsigned short u16;
typedef __attribute__((ext_vector_type(8))) unsigned short u16x8;

#define GLOBAL_AS __attribute__((address_space(1)))
#define LDS_AS    __attribute__((address_space(3)))

__device__ __forceinline__ void load_lds16(const void* g, void* l) {
    __builtin_amdgcn_global_load_lds((const GLOBAL_AS void*)g, (LDS_AS void*)l, 16, 0, 0);
}

__device__ __forceinline__ u16 f2bf(float f) {
    union { float f; uint32_t u; } v; v.f = f;
    uint32_t r = v.u + 0x7FFFu + ((v.u >> 16) & 1u);   // RNE
    return (u16)(r >> 16);
}
__device__ __forceinline__ float b2f(u16 b) {
    union { uint32_t u; float f; } v; v.u = ((uint32_t)b) << 16;
    return v.f;
}

// ---------- aux: fp32 -> bf16 convert with zero-padding ----------
__global__ void k_conv_pad(const float* __restrict__ in, u16* __restrict__ out,
                           int rIn, int cIn, int cOut, int total8) {
    int idx = blockIdx.x * blockDim.x + threadIdx.x;
    if (idx >= total8) return;
    int c8n = cOut >> 3;
    int r  = idx / c8n;
    int c0 = (idx - r * c8n) << 3;
    u16x8 o;
#pragma unroll
    for (int j = 0; j < 8; ++j) {
        int c = c0 + j;
        o[j] = (r < rIn && c < cIn) ? f2bf(in[(size_t)r * cIn + c]) : (u16)0;
    }
    *(u16x8*)(out + (size_t)r * cOut + c0) = o;
}

// ---------- aux: fp32 [kIn x nIn] -> bf16 transposed [nOut x kOut], zero-padded ----------
__global__ void k_transpose_conv(const float* __restrict__ in, u16* __restrict__ out,
                                 int kIn, int nIn, int kOut) {
    __shared__ float tile[32][33];
    int k0 = blockIdx.x * 32, n0 = blockIdx.y * 32;
    int tx = threadIdx.x, ty = threadIdx.y;   // block (32,8)
#pragma unroll
    for (int i = 0; i < 4; ++i) {
        int k = k0 + ty + i * 8, n = n0 + tx;
        tile[ty + i * 8][tx] = (k < kIn && n < nIn) ? in[(size_t)k * nIn + n] : 0.f;
    }
    __syncthreads();
#pragma unroll
    for (int i = 0; i < 4; ++i) {
        int n = n0 + ty + i * 8, k = k0 + tx;
        out[(size_t)n * kOut + k] = f2bf(tile[tx][ty + i * 8]);
    }
}

// ---------- old 128x128 kernel (kept for G3: proven at 4 blocks/CU) ----------
template <int MODE>
__global__ __launch_bounds__(256, 4) void k_gemm_bt(
    const u16* __restrict__ A, const u16* __restrict__ B,
    const u16* __restrict__ bias, void* __restrict__ Cv,
    int K, int ldc, int mReal, int nReal) {
    (void)bias;
    __shared__ __align__(16) char lds[32768];
    char* As = lds;
    char* Bs = lds + 16384;

    const int tid  = threadIdx.x;
    const int w    = tid >> 6, lane = tid & 63;
    const int l31  = lane & 31, hi = lane >> 5;
    const int wm   = (w & 1) * 64, wn = (w >> 1) * 64;
    const int bm   = blockIdx.y * 128, bn = blockIdx.x * 128;

    const int srcRow = tid >> 3;
    const int srcCol = (tid & 7) ^ (srcRow & 7);
    const u16* aSrc = A + (size_t)(bm + srcRow) * K + (srcCol << 3);
    const u16* bSrc = B + (size_t)(bn + srcRow) * K + (srcCol << 3);
    char* aDst = As + ((tid & ~63) << 4);
    char* bDst = Bs + ((tid & ~63) << 4);

    const int aRow0 = (wm + l31) * 128;
    const int aRow1 = (wm + 32 + l31) * 128;
    const int bRow0 = (wn + l31) * 128;
    const int bRow1 = (wn + 32 + l31) * 128;

    f32x16 acc[2][2];
#pragma unroll
    for (int i = 0; i < 2; ++i)
#pragma unroll
        for (int j = 0; j < 2; ++j) acc[i][j] = (f32x16)(0.f);

    for (int k0 = 0; k0 < K; k0 += 64) {
#pragma unroll
        for (int t = 0; t < 4; ++t) {
            load_lds16(aSrc + (size_t)(t * 32) * K, aDst + t * 4096);
            load_lds16(bSrc + (size_t)(t * 32) * K, bDst + t * 4096);
        }
        aSrc += 64; bSrc += 64;
        __syncthreads();
#pragma unroll
        for (int ks = 0; ks < 4; ++ks) {
            const int swz = (((ks * 2 + hi) ^ (l31 & 7)) << 4);
            bf16x8 af[2], bfr[2];
            af[0]  = *(const bf16x8*)(As + aRow0 + swz);
            af[1]  = *(const bf16x8*)(As + aRow1 + swz);
            bfr[0] = *(const bf16x8*)(Bs + bRow0 + swz);
            bfr[1] = *(const bf16x8*)(Bs + bRow1 + swz);
#pragma unroll
            for (int mi = 0; mi < 2; ++mi)
#pragma unroll
                for (int ni = 0; ni < 2; ++ni)
                    acc[mi][ni] = __builtin_amdgcn_mfma_f32_32x32x16_bf16(
                        af[mi], bfr[ni], acc[mi][ni], 0, 0, 0);
        }
        __syncthreads();
    }

    float bv[2];
    if (MODE >= 1) {
#pragma unroll
        for (int ni = 0; ni < 2; ++ni) bv[ni] = b2f(bias[bn + wn + ni * 32 + l31]);
    }
#pragma unroll
    for (int mi = 0; mi < 2; ++mi) {
#pragma unroll
        for (int reg = 0; reg < 16; ++reg) {
            int row = bm + wm + mi * 32 + (reg & 3) + 8 * (reg >> 2) + 4 * hi;
#pragma unroll
            for (int ni = 0; ni < 2; ++ni) {
                int col = bn + wn + ni * 32 + l31;
                float v = acc[mi][ni][reg];
                if (MODE == 0) {
                    if (row < mReal && col < nReal)
                        ((u16*)Cv)[(size_t)row * ldc + col] = f2bf(v);
                } else if (MODE == 1) {
                    v += bv[ni];
                    v = v > 0.f ? v : 0.f;
                    ((u16*)Cv)[(size_t)row * ldc + col] = f2bf(v);
                } else {
                    ((float*)Cv)[(size_t)row * ldc + col] = v + bv[ni];
                }
            }
        }
    }
}

// ---------- 256x128 2-blocks/CU GEMM, R9: conflict-free LDS + cross-block overlap ----------
// R8 post-mortem: intra-wave cross-phase prefetch spilled (WRITE_SIZE 69->284 MB =
// scratch; 24 live frags + 128 acc + pinned scheduler > 256 VGPR). Revert to R7's
// in-phase reads; get the LDS||MFMA overlap from a SECOND CO-RESIDENT BLOCK instead
// (zero extra registers; m114: co-resident waves' MFMA covers the other block's
// LDS/stage/barrier-drain phases). R7's 128 KiB LDS forced 1 block/CU — this kernel:
//   tile 256x128, 4 waves (2M x 2N, per-wave 128x64), BK=32, double-buffered
//   LDS 48 KiB -> 2 blocks/CU at 256 threads, launch_bounds(256,2), ~200 VGPR.
// Conflict-free layout (R7-proven family, adapted to 64-B rows / 4 slots):
//   LDS row r holds its 4 16-B k-chunks at slot c ^ (r&3). Frag read: lane(l15,lg4)
//   reads row l15, chunk lg4 at slot lg4^(l15&3) -> granule 4*l15 + slot, all 64
//   lanes distinct -> exactly 2 lanes/bank (free). Staged via pre-swizzled global
//   source (cOrig = (lane&3)^((lane>>2)&3)), linear LDS dest (rule #21).
// Sync ledger per 64-K iter (R4's proven 2-barrier form):
//   STAGE6(buf1); RD12(buf0); lgkm0; MM32; vmcnt0+BAR   (buf1 landed; buf0 drained)
//   restage buf0; RD12(buf1); lgkm0; MM32; vmcnt0+BAR   (buf0 landed)
// The vmcnt0 drain stall is the co-resident block's compute window.

#define BARRIER() do { asm volatile("" ::: "memory"); \
                       __builtin_amdgcn_s_barrier(); \
                       asm volatile("" ::: "memory"); } while (0)
#define LGKM0()   do { asm volatile("s_waitcnt lgkmcnt(0)" ::: "memory"); \
                       __builtin_amdgcn_sched_barrier(0); } while (0)
#define VMCNT0()  do { asm volatile("s_waitcnt vmcnt(0)" ::: "memory"); \
                       __builtin_amdgcn_sched_barrier(0); } while (0)

// 6 global_load_lds: 4 A-sweeps (64 rows) + 2 B-sweeps for K-tile at elem offset koff
#define STAGE6(bb, koff) do { \
    _Pragma("unroll") for (int t_ = 0; t_ < 4; ++t_) \
        load_lds16(aS + (koff) + (size_t)(t_ * 64) * K, (bb) + t_ * 4096 + ldsW); \
    _Pragma("unroll") for (int t_ = 0; t_ < 2; ++t_) \
        load_lds16(bS + (koff) + (size_t)(t_ * 64) * K, (bb) + 16384 + t_ * 4096 + ldsW); \
} while (0)

// 12 conflict-free frag reads for one 32-K tile
#define RD12(bb) do { \
    _Pragma("unroll") for (int mi = 0; mi < 8; ++mi) \
        fa[mi] = *(const bf16x8*)((bb) + aRd + mi * 1024); \
    _Pragma("unroll") for (int ni = 0; ni < 4; ++ni) \
        fb[ni] = *(const bf16x8*)((bb) + bRd + ni * 1024); \
} while (0)

// 32 MFMA (one 32-K tile), 32 independent chains
#define MM32() do { \
    __builtin_amdgcn_s_setprio(1); \
    _Pragma("unroll") for (int ni = 0; ni < 4; ++ni) \
    _Pragma("unroll") for (int mi = 0; mi < 8; ++mi) \
        acc[mi][ni] = __builtin_amdgcn_mfma_f32_16x16x32_bf16( \
            fa[mi], fb[ni], acc[mi][ni], 0, 0, 0); \
    __builtin_amdgcn_s_setprio(0); \
} while (0)

template <int MODE>
__global__ __launch_bounds__(256, 2) void k_gemm2b(
    const u16* __restrict__ A, const u16* __restrict__ B,
    const u16* __restrict__ bias, void* __restrict__ Cv,
    int K, int ldc, int mReal, int nReal, int gx) {
    __shared__ __align__(16) char lds[49152];   // 2 x 24 KiB buffers

    const int tid  = threadIdx.x;
    const int w    = tid >> 6, lane = tid & 63;
    const int l15  = lane & 15, lg4 = lane >> 4;
    const int wr   = w & 1, wc = w >> 1;            // 2x2 wave grid, per-wave 128x64

    // bijective XCD-chunked swizzle (m204 form)
    const int nwg = (int)gridDim.x;
    const int q   = nwg >> 3, r = nwg & 7;
    const int xcd = (int)blockIdx.x & 7, lid = (int)blockIdx.x >> 3;
    const int wg  = (xcd < r ? xcd * (q + 1) : r * (q + 1) + (xcd - r) * q) + lid;
    const int bm  = (wg / gx) * 256;
    const int bn  = (wg % gx) * 128;

    char* const buf0 = lds;            // A [256r][64B] slot-swz; B at +16384 [128r][64B]
    char* const buf1 = lds + 24576;

    // staging: pre-swizzled source chunk, linear LDS dest (wave w covers 16 rows/sweep)
    const int cOrig = (lane & 3) ^ ((lane >> 2) & 3);
    const int sRow  = w * 16 + (lane >> 2);          // +64 per sweep
    const int ldsW  = w * 1024;                      // wave slot per sweep

    // conflict-free frag-read bases (slot = lg4 ^ (l15&3))
    const int slotOff = ((lg4 ^ (l15 & 3)) << 4);
    const int aRd = (wr * 128 + l15) * 64 + slotOff;           // + mi*1024
    const int bRd = 16384 + (wc * 64 + l15) * 64 + slotOff;    // + ni*1024

    const u16* const aS = A + (size_t)(bm + sRow) * K + cOrig * 8;
    const u16* const bS = B + (size_t)(bn + sRow) * K + cOrig * 8;

    f32x4 acc[8][4];
#pragma unroll
    for (int i = 0; i < 8; ++i)
#pragma unroll
        for (int j = 0; j < 4; ++j) acc[i][j] = (f32x4)(0.f);

    bf16x8 fa[8], fb[4];

    // prologue: K-tile 0 -> buf0
    STAGE6(buf0, 0);
    VMCNT0();
    BARRIER();

    const int nIt = K >> 6;            // 64-K pairs (all K are multiples of 64)
    size_t ko = 0;
#pragma unroll 1
    for (int it = 0; it < nIt; ++it) {
        STAGE6(buf1, ko + 32);           // buf1 free since last barrier
        RD12(buf0);
        LGKM0();
        MM32();
        VMCNT0(); BARRIER();             // buf1 landed; all waves' buf0 reads drained
        if (it + 1 < nIt) { STAGE6(buf0, ko + 64); }
        RD12(buf1);
        LGKM0();
        MM32();
        VMCNT0(); BARRIER();             // buf0 landed
        ko += 64;
    }

    // epilogue. 16x16 C/D layout (m89/m91): col = lane&15, row = (lane>>4)*4 + reg
    float bv[4];
    if (MODE >= 1) {
#pragma unroll
        for (int ni = 0; ni < 4; ++ni) bv[ni] = b2f(bias[bn + wc * 64 + ni * 16 + l15]);
    }
#pragma unroll
    for (int mi = 0; mi < 8; ++mi) {
#pragma unroll
        for (int ni = 0; ni < 4; ++ni) {
#pragma unroll
            for (int rg = 0; rg < 4; ++rg) {
                const int row = bm + wr * 128 + mi * 16 + lg4 * 4 + rg;
                const int col = bn + wc * 64 + ni * 16 + l15;
                float vv = acc[mi][ni][rg];
                if (MODE == 0) {
                    if (row < mReal && col < nReal)
                        ((u16*)Cv)[(size_t)row * ldc + col] = f2bf(vv);
                } else if (MODE == 1) {
                    vv += bv[ni];
                    vv = vv > 0.f ? vv : 0.f;
                    ((u16*)Cv)[(size_t)row * ldc + col] = f2bf(vv);
                } else {
                    ((float*)Cv)[(size_t)row * ldc + col] = vv + bv[ni];
                }
            }
        }
    }
}

// ---------- launch ----------
// Sizes: D_IN=2048, D_H=4096, D_OUT=2048, B=4096; SIZE_N=5794, SIZE_M=2897
// Padded GEMM0 dims: M=N=5888 (23*256 / 46*128), K=2944
// Vf flat unpack offsets (elems):
//   W1 @ 0, b1 @ 8388608, W2 @ 8392704, b2 @ 25169920, W3 @ 25174016, b3 @ 33562624
extern "C" void kernel_launch(void* const* d_in, const int* in_sizes, int n_in,
                              void* d_out, int out_size, void* d_ws, size_t ws_size,
                              hipStream_t stream) {
    (void)in_sizes; (void)n_in; (void)out_size; (void)ws_size;
    const float* x  = (const float*)d_in[0];
    const float* V1 = (const float*)d_in[1];
    const float* V2 = (const float*)d_in[2];

    char* ws = (char*)d_ws;
    u16* Vf   = (u16*)(ws);                            // 5794*5794 bf16 -> 67,140,872 B
    u16* V1b  = (u16*)(ws + 67141120);                 // [5888 x 2944] bf16 = 34,668,544 B
    u16* V2bT = (u16*)(ws + 67141120 + 34668544);      // [5888 x 2944] bf16
    u16* Xb   = (u16*)(ws + 67141120 + 2 * 34668544);  // [4096 x 2048] bf16
    u16* H1   = V1b;   // dead after GEMM0
    u16* H2   = V2bT;

    k_conv_pad<<<8464, 256, 0, stream>>>(V1, V1b, 5794, 2897, 2944, 5888 * 2944 / 8);
    k_transpose_conv<<<dim3(92, 184), dim3(32, 8), 0, stream>>>(V2, V2bT, 2897, 5794, 2944);
    k_conv_pad<<<4096, 256, 0, stream>>>(x, Xb, 4096, 2048, 2048, 4096 * 2048 / 8);

    // G0: Vf = V1 @ V2  (padded 5888x5888x2944; 23x46 = 1058 tiles, 2 blocks/CU)
    k_gemm2b<0><<<1058, 256, 0, stream>>>(V1b, V2bT, nullptr, Vf,
                                          2944, 5794, 5794, 5794, 46);
    // G1: H1 = relu(Xb @ W1^T + b1)   [4096x4096], K=2048 (16x32 = 512 = exactly 2/CU)
    k_gemm2b<1><<<512, 256, 0, stream>>>(Xb, Vf + 0, Vf + 8388608, H1,
                                         2048, 4096, 4096, 4096, 32);
    // G2: H2 = relu(H1 @ W2^T + b2)   [4096x4096], K=4096
    k_gemm2b<1><<<512, 256, 0, stream>>>(H1, Vf + 8392704, Vf + 25169920, H2,
                                         4096, 4096, 4096, 4096, 32);
    // G3: out = H2 @ W3^T + b3        [4096x2048] fp32, K=4096 (old 128^2 kernel)
    k_gemm_bt<2><<<dim3(16, 32), 256, 0, stream>>>(H2, Vf + 25174016, Vf + 33562624, d_out,
                                                   4096, 2048, 4096, 2048);
}